// Round 21
// baseline (1503.838 us; speedup 1.0000x reference)
//
#include <hip/hip_runtime.h>
#include <math.h>

#define BATCH 64
#define NN 512
#define MS 511                       // minor size (root row/col removed)
#define LDM 512                      // row stride
#define MSTRIDE ((size_t)MS*LDM)
#define OSTRIDE ((size_t)NN*NN)
#define PB 64
// Yt[512][32] words; 4-word rotation by row-octet -> b128-aligned, even bank spread
#define YW(r,c) (((r)<<5) + ((((c) + ((((r)>>3)&7)<<2))) & 31))

// ---- input conversion + gold score + mask count (fused, one pass) ----
__global__ void k_convert_gold(const void* __restrict__ mask_raw,
                               const void* __restrict__ tgt_raw,
                               const float* __restrict__ scores,
                               int* __restrict__ cmask, int* __restrict__ ctgt,
                               double* __restrict__ goldb, int* __restrict__ cntb) {
  int b = blockIdx.x;
  const unsigned char* mb = (const unsigned char*)mask_raw;
  const int* mw = (const int*)mask_raw;
  const int* tw = (const int*)tgt_raw;
  bool m_bytes = (mb[1] | mb[2] | mb[3]) != 0;
  bool m_64 = false;
  if (!m_bytes) {
    int acc = 0;
    for (int j = 1; j < 32; j += 2) acc |= mw[j];
    m_64 = (acc == 0);
  }
  int tacc = 0;
  for (int j = 1; j < 32; j += 2) tacc |= tw[j];
  bool t_64 = (tacc == 0);
  int tid = threadIdx.x;
  double g = 0.0;
  int c = 0;
  for (int i = tid; i < NN; i += 256) {
    size_t idx = (size_t)b * NN + i;
    int mv;
    if (m_bytes) mv = mb[idx] != 0;
    else if (m_64) mv = mw[2 * idx] != 0;
    else mv = mw[idx] != 0;
    int tv = t_64 ? tw[2 * idx] : tw[idx];
    cmask[idx] = mv;
    ctgt[idx] = tv;
    if (mv) {
      g += (double)scores[((size_t)b * NN + i) * NN + tv];
      c++;
    }
  }
  __shared__ double gs[256];
  __shared__ int cs[256];
  gs[tid] = g;
  cs[tid] = c;
  __syncthreads();
  for (int s = 128; s > 0; s >>= 1) {
    if (tid < s) { gs[tid] += gs[tid + s]; cs[tid] += cs[tid + s]; }
    __syncthreads();
  }
  if (tid == 0) { goldb[b] = gs[0]; cntb[b] = cs[0]; }
}

// ---- build Laplacian minor M[b]; pad column (index MS) zeroed ----
__global__ void k_build_M(const float* __restrict__ scores,
                          const int* __restrict__ mask,
                          float* __restrict__ M) {
  int b = blockIdx.y;
  int ip = blockIdx.x;
  int i = ip + 1;
  const int* mrow = mask + (size_t)b * NN;
  float* Mrow = M + (size_t)b * MSTRIDE + (size_t)ip * LDM;
  int tid = threadIdx.x;
  if (!mrow[i]) {
    for (int jp = tid; jp < MS; jp += 256)
      Mrow[jp] = (jp == ip) ? 1.0f : 0.0f;
    if (tid == 0) Mrow[MS] = 0.0f;
    return;
  }
  const float* srow = scores + ((size_t)b * NN + i) * NN;
  double part = 0.0;
  for (int j = tid; j < NN; j += 256) {
    bool mj = (j == 0) || (mrow[j] != 0);
    float e = mj ? expf(srow[j]) : 0.0f;
    part += (double)e;
    if (j >= 1) Mrow[j - 1] = -e;
  }
  __shared__ double red[256];
  red[tid] = part;
  __syncthreads();
  for (int s = 128; s > 0; s >>= 1) {
    if (tid < s) red[tid] += red[tid + s];
    __syncthreads();
  }
  if (tid == (i & 255)) Mrow[ip] += (float)red[0];
  if (tid == 0) Mrow[MS] = 0.0f;
}

// ---- factor 64x64 diag block (512 thr, 8 subs); write PACKED inv ----
__global__ __launch_bounds__(512) void k_panel64(float* __restrict__ M, int kb,
                                                 double* __restrict__ ld2) {
  int b = blockIdx.x;
  float* Mb = M + (size_t)b * MSTRIDE;
  int tid = threadIdx.x;
  __shared__ float A[64 * 65];
  __shared__ float XU[64 * 66];
  __shared__ float XL[64 * 66];
  __shared__ double lg[64];

  for (int idx = tid; idx < 64 * 64; idx += 512) {
    int r = idx >> 6, c = idx & 63;
    int gr = kb + r, gc = kb + c;
    A[r * 65 + c] = (gr < MS && gc < MS) ? Mb[(size_t)gr * LDM + gc]
                                         : ((r == c) ? 1.0f : 0.0f);
  }
  __syncthreads();

  int rr = tid >> 3, sub = tid & 7;   // 8 subs per row, same wave
  for (int j = 0; j < 63; ++j) {
    if (rr > j) {
      float piv = A[j * 65 + j];
      float l = A[rr * 65 + j] / piv;  // all subs read before sub0 writes
      if (sub == 0) A[rr * 65 + j] = l;
      for (int c = j + 1 + sub; c < 64; c += 8)
        A[rr * 65 + c] -= l * A[j * 65 + c];
    }
    __syncthreads();
  }
  if (tid < 64) lg[tid] = log(fabs((double)A[tid * 65 + tid]));
  __syncthreads();
  if (tid == 0) {
    double a = 0.0;
    for (int j = 0; j < 64; ++j) a += lg[j];
    ld2[(kb >> 6) * BATCH + b] = a;
  }

  // invU column rr
  {
    int c = rr;
    if (sub == 0) XU[c * 66 + c] = 1.0f / A[c * 65 + c];
    for (int r2 = c - 1; r2 >= 0; --r2) {
      float s = 0.0f;
      for (int k = r2 + 1 + sub; k <= c; k += 8)
        s += A[r2 * 65 + k] * XU[c * 66 + k];
      s += __shfl_xor(s, 1, 8);
      s += __shfl_xor(s, 2, 8);
      s += __shfl_xor(s, 4, 8);
      if (sub == 0) XU[c * 66 + r2] = -s / A[r2 * 65 + r2];
    }
  }
  // invL column rr (unit lower)
  {
    int c = rr;
    if (sub == 0) XL[c * 66 + c] = 1.0f;
    for (int r2 = c + 1; r2 < 64; ++r2) {
      float s = 0.0f;
      for (int k = c + sub; k < r2; k += 8)
        s += A[r2 * 65 + k] * XL[c * 66 + k];
      s += __shfl_xor(s, 1, 8);
      s += __shfl_xor(s, 2, 8);
      s += __shfl_xor(s, 4, 8);
      if (sub == 0) XL[c * 66 + r2] = -s;
    }
  }
  __syncthreads();
  // packed write into diag block of M
  for (int idx = tid; idx < 4096; idx += 512) {
    int r = idx >> 6, c = idx & 63;
    int gr = kb + r, gc = kb + c;
    if (gr < MS && gc < MS)
      Mb[(size_t)gr * LDM + gc] = (r > c) ? XL[c * 66 + r] : XU[c * 66 + r];
  }
}

// ---- TRSM-as-GEMM using packed inv: side0: U12 = invL*A12 ; side1: L21 = A21*invU ----
__global__ __launch_bounds__(256) void k_trsm(float* __restrict__ M, int kb) {
  int b = blockIdx.z;
  int t = blockIdx.x;
  int side = blockIdx.y;
  float* Mb = M + (size_t)b * MSTRIDE;
  __shared__ float Fs[64 * 65];
  __shared__ float As[64 * 65];
  int tid = threadIdx.x;
  int off = kb + 64 + t * 64;
  for (int idx = tid; idx < 4096; idx += 256) {
    int r = idx >> 6, c = idx & 63;
    int gr = kb + r, gc = kb + c;
    float v;
    if (gr < MS && gc < MS) {
      float d = Mb[(size_t)gr * LDM + gc];
      if (side == 0) v = (r > c) ? d : (r == c ? 1.0f : 0.0f);   // invL
      else           v = (r <= c) ? d : 0.0f;                    // invU
    } else {
      v = (r == c) ? 1.0f : 0.0f;                                // pad identity
    }
    Fs[r * 65 + c] = v;
  }
  for (int idx = tid; idx < 4096; idx += 256) {
    int r = idx >> 6, c = idx & 63;
    int gr, gc;
    if (side == 0) { gr = kb + r; gc = off + c; }
    else           { gr = off + r; gc = kb + c; }
    As[r * 65 + c] = (gr < MS && gc < MS) ? Mb[(size_t)gr * LDM + gc] : 0.0f;
  }
  __syncthreads();
  int tx = tid & 15, ty = tid >> 4;
  float acc[4][4];
#pragma unroll
  for (int i = 0; i < 4; ++i)
#pragma unroll
    for (int j = 0; j < 4; ++j) acc[i][j] = 0.0f;
  if (side == 0) {
#pragma unroll 4
    for (int k = 0; k < 64; ++k) {
      float av[4], bv[4];
#pragma unroll
      for (int i = 0; i < 4; ++i) av[i] = Fs[(ty * 4 + i) * 65 + k];
#pragma unroll
      for (int j = 0; j < 4; ++j) bv[j] = As[k * 65 + tx * 4 + j];
#pragma unroll
      for (int i = 0; i < 4; ++i)
#pragma unroll
        for (int j = 0; j < 4; ++j) acc[i][j] = fmaf(av[i], bv[j], acc[i][j]);
    }
  } else {
#pragma unroll 4
    for (int k = 0; k < 64; ++k) {
      float av[4], bv[4];
#pragma unroll
      for (int i = 0; i < 4; ++i) av[i] = As[(ty * 4 + i) * 65 + k];
#pragma unroll
      for (int j = 0; j < 4; ++j) bv[j] = Fs[k * 65 + tx * 4 + j];
#pragma unroll
      for (int i = 0; i < 4; ++i)
#pragma unroll
        for (int j = 0; j < 4; ++j) acc[i][j] = fmaf(av[i], bv[j], acc[i][j]);
    }
  }
  if (side == 0) {                     // rows kb..kb+63 (<MS); col-511 store = 0 ok
    int gc = off + tx * 4;
    if (gc < MS) {
#pragma unroll
      for (int i = 0; i < 4; ++i) {
        int gr = kb + ty * 4 + i;
        *(float4*)&Mb[(size_t)gr * LDM + gc] =
            make_float4(acc[i][0], acc[i][1], acc[i][2], acc[i][3]);
      }
    }
  } else {                             // cols kb..kb+63 (<MS); guard rows
#pragma unroll
    for (int i = 0; i < 4; ++i) {
      int gr = off + ty * 4 + i;
      if (gr < MS)
        *(float4*)&Mb[(size_t)gr * LDM + kb + tx * 4] =
            make_float4(acc[i][0], acc[i][1], acc[i][2], acc[i][3]);
    }
  }
}

// ---- trailing rank-64 update: C -= L21 * U12, 128x128 tiles, float4 C I/O ----
__global__ __launch_bounds__(256) void k_update(float* __restrict__ M, int kb) {
  int b = blockIdx.z;
  float* Mb = M + (size_t)b * MSTRIDE;
  int row0 = kb + PB + blockIdx.x * 128;
  int col0 = kb + PB + blockIdx.y * 128;
  __shared__ __align__(16) float As[128 * 68];
  __shared__ __align__(16) float Bs[64 * 132];
  int tid = threadIdx.x;
  for (int idx = tid; idx < 2048; idx += 256) {
    int r = idx >> 4, q = (idx & 15) * 4;
    int gr = row0 + r;
    float4 v = make_float4(0.f, 0.f, 0.f, 0.f);
    if (gr < MS) v = *(const float4*)&Mb[(size_t)gr * LDM + kb + q];
    *(float4*)&As[r * 68 + q] = v;
  }
  for (int idx = tid; idx < 2048; idx += 256) {
    int r = idx >> 5, q = (idx & 31) * 4;
    int gc = col0 + q;
    float4 v = make_float4(0.f, 0.f, 0.f, 0.f);
    if (gc < MS)                       // col 511 is maintained 0 in M
      v = *(const float4*)&Mb[(size_t)(kb + r) * LDM + gc];
    *(float4*)&Bs[r * 132 + q] = v;
  }
  __syncthreads();
  int tx = tid & 15, ty = tid >> 4;
  int gc0 = col0 + tx * 4, gc1 = gc0 + 64;
  bool c0v = gc0 < MS, c1v = gc1 < MS;
  float4 acc[8][2];
#pragma unroll
  for (int i = 0; i < 8; ++i) {
    int gr = row0 + ty + 16 * i;
    bool rv = gr < MS;
    acc[i][0] = (rv && c0v) ? *(const float4*)&Mb[(size_t)gr * LDM + gc0]
                            : make_float4(0.f, 0.f, 0.f, 0.f);
    acc[i][1] = (rv && c1v) ? *(const float4*)&Mb[(size_t)gr * LDM + gc1]
                            : make_float4(0.f, 0.f, 0.f, 0.f);
  }
#pragma unroll 2
  for (int k = 0; k < 64; ++k) {
    float4 b0 = *(const float4*)&Bs[k * 132 + tx * 4];
    float4 b1 = *(const float4*)&Bs[k * 132 + tx * 4 + 64];
    float av[8];
#pragma unroll
    for (int i = 0; i < 8; ++i) av[i] = As[(ty + 16 * i) * 68 + k];
#pragma unroll
    for (int i = 0; i < 8; ++i) {
      float a = av[i];
      acc[i][0].x = fmaf(-a, b0.x, acc[i][0].x);
      acc[i][0].y = fmaf(-a, b0.y, acc[i][0].y);
      acc[i][0].z = fmaf(-a, b0.z, acc[i][0].z);
      acc[i][0].w = fmaf(-a, b0.w, acc[i][0].w);
      acc[i][1].x = fmaf(-a, b1.x, acc[i][1].x);
      acc[i][1].y = fmaf(-a, b1.y, acc[i][1].y);
      acc[i][1].z = fmaf(-a, b1.z, acc[i][1].z);
      acc[i][1].w = fmaf(-a, b1.w, acc[i][1].w);
    }
  }
#pragma unroll
  for (int i = 0; i < 8; ++i) {
    int gr = row0 + ty + 16 * i;
    if (gr < MS) {
      if (c0v) *(float4*)&Mb[(size_t)gr * LDM + gc0] = acc[i][0];
      if (c1v) *(float4*)&Mb[(size_t)gr * LDM + gc1] = acc[i][1];
    }
  }
}

// ======== k_solve v13: R17 tiling + diag-load hoist across barrier (T14) ========
// diag rows are preloaded from global BEFORE the pass-entry barrier (M is
// read-only in this kernel, so hoisting over the LDS barrier is safe).
__device__ __forceinline__ void diag_pass_pre(float* __restrict__ Yt,
                                              int jb, int tid, int UPPER,
                                              const float4* __restrict__ td) {
  int drg = tid >> 3, dcg = tid & 7;   // 64 rows x 8 col-groups (4 cols each)
  float4 da = make_float4(0.f, 0.f, 0.f, 0.f);
#pragma unroll 4
  for (int q = 0; q < 16; ++q) {
    float4 t = td[q];
#pragma unroll
    for (int m = 0; m < 4; ++m) {
      int cc = 4 * q + m;
      float tm = (m == 0) ? t.x : ((m == 1) ? t.y : ((m == 2) ? t.z : t.w));
      float a;
      if (UPPER) a = (drg <= cc) ? tm : 0.0f;
      else       a = (drg > cc) ? tm : ((drg == cc) ? 1.0f : 0.0f);
      float4 bv = *(const float4*)&Yt[YW(jb + cc, 4 * dcg)];
      da.x = fmaf(a, bv.x, da.x); da.y = fmaf(a, bv.y, da.y);
      da.z = fmaf(a, bv.z, da.z); da.w = fmaf(a, bv.w, da.w);
    }
  }
  __syncthreads();                 // all reads of Y[jb] done before overwrite
  *(float4*)&Yt[YW(jb + drg, 4 * dcg)] = da;
  __syncthreads();
}

// off-diag: rows [rowBase, rowBase+nr) -= A(rows, jb..jb+63) * Y[jb..jb+63]
__device__ __forceinline__ void offdiag_pass(const float* __restrict__ Mb,
                                             float* __restrict__ Yt,
                                             int jb, int rowBase, int nr,
                                             int tid, int cg, int rg) {
  if (nr <= 0) return;
  int row0 = rowBase + 8 * rg;
  int nv = nr - 8 * rg;
  if (nv <= 0) return;
  nv = nv > 8 ? 8 : nv;
  float4 a0[8];
#pragma unroll
  for (int i = 0; i < 8; ++i)
    a0[i] = (i < nv) ? *(const float4*)&Yt[YW(row0 + i, 4 * cg)]
                     : make_float4(0.f, 0.f, 0.f, 0.f);
  const float* Ar = Mb + (size_t)row0 * LDM + jb;
#pragma unroll 2
  for (int kh = 0; kh < 16; ++kh) {
    float4 pA[8];
#pragma unroll
    for (int i = 0; i < 8; ++i)
      pA[i] = (i < nv) ? *(const float4*)&Ar[(size_t)i * LDM + 4 * kh]
                       : make_float4(0.f, 0.f, 0.f, 0.f);
    __builtin_amdgcn_s_setprio(1);
#pragma unroll
    for (int k = 0; k < 4; ++k) {
      float4 bv = *(const float4*)&Yt[YW(jb + 4 * kh + k, 4 * cg)];
#define AK(i) ((k == 0) ? pA[i].x : ((k == 1) ? pA[i].y : ((k == 2) ? pA[i].z : pA[i].w)))
#define RF(i) { \
      float av_ = AK(i); \
      a0[i].x = fmaf(-av_, bv.x, a0[i].x); a0[i].y = fmaf(-av_, bv.y, a0[i].y); \
      a0[i].z = fmaf(-av_, bv.z, a0[i].z); a0[i].w = fmaf(-av_, bv.w, a0[i].w); }
      RF(0) RF(1) RF(2) RF(3) RF(4) RF(5) RF(6) RF(7)
#undef RF
#undef AK
    }
    __builtin_amdgcn_s_setprio(0);
  }
#pragma unroll
  for (int i = 0; i < 8; ++i) {
    if (i < nv)
      *(float4*)&Yt[YW(row0 + i, 4 * cg)] = a0[i];
  }
}

__global__ __launch_bounds__(512, 4) void k_solve(const float* __restrict__ M,
                                                  const float* __restrict__ scores,
                                                  const int* __restrict__ mask,
                                                  float* __restrict__ out1) {
  int id = blockIdx.x;
  int xcd = id & 7, k7 = id >> 3;
  int b = xcd + ((k7 >> 4) << 3);      // 8 batches per XCD, sequential
  int cb = k7 & 15;                    // column block 0..15
  const float* Mb = M + (size_t)b * MSTRIDE;
  int tid = threadIdx.x;
  int c0 = cb * 32, fb = c0 & ~63;
  __shared__ __align__(16) float Yt[512 * 32];   // 65536 B -> 2 WG/CU (16 waves)
  int cg = tid & 7, rg = tid >> 3;
  int drg = tid >> 3;                  // diag row for this thread

  for (int idx = tid; idx < 4096; idx += 512)
    ((float4*)Yt)[idx] = make_float4(0.f, 0.f, 0.f, 0.f);
  __syncthreads();
  {  // init rows fb..fb+63 = packed invL columns (c0-fb)..+31
    int coff = c0 - fb;
    int r2 = tid >> 3, q4 = (tid & 7) << 2;      // exactly 512 work items
    int gr = fb + r2;
    int c_ = coff + q4;
    float e0, e1, e2, e3;
    if (gr < MS) {
      float4 d = *(const float4*)&Mb[(size_t)gr * LDM + fb + c_];
      e0 = (r2 > c_) ? d.x : ((r2 == c_) ? 1.f : 0.f);
      e1 = (r2 > c_ + 1) ? d.y : ((r2 == c_ + 1) ? 1.f : 0.f);
      e2 = (r2 > c_ + 2) ? d.z : ((r2 == c_ + 2) ? 1.f : 0.f);
      e3 = (r2 > c_ + 3) ? d.w : ((r2 == c_ + 3) ? 1.f : 0.f);
    } else {
      e0 = (r2 == c_) ? 1.f : 0.f;
      e1 = (r2 == c_ + 1) ? 1.f : 0.f;
      e2 = (r2 == c_ + 2) ? 1.f : 0.f;
      e3 = (r2 == c_ + 3) ? 1.f : 0.f;
    }
    *(float4*)&Yt[YW(gr, q4)] = make_float4(e0, e1, e2, e3);
  }
  __syncthreads();

  // forward: L Y = I
  for (int jb = fb; jb < MS; jb += 64) {
    if (jb > fb) {
      float4 td[16];                   // preload diag row BEFORE barrier (global-only)
      {
        int dr = jb + drg;
        bool vr = dr < MS;
        const float* Pr = Mb + (size_t)dr * LDM + jb;
#pragma unroll
        for (int q = 0; q < 16; ++q)
          td[q] = vr ? *(const float4*)&Pr[4 * q] : make_float4(0.f, 0.f, 0.f, 0.f);
      }
      __syncthreads();                 // offdiag writes to Yt visible
      diag_pass_pre(Yt, jb, tid, 0, td);
    }
    offdiag_pass(Mb, Yt, jb, jb + 64, MS - (jb + 64), tid, cg, rg);
  }
  // backward: U X = Y
  for (int jb = 448; jb >= 0; jb -= 64) {
    float4 td[16];
    {
      int dr = jb + drg;
      bool vr = dr < MS;
      const float* Pr = Mb + (size_t)dr * LDM + jb;
#pragma unroll
      for (int q = 0; q < 16; ++q)
        td[q] = vr ? *(const float4*)&Pr[4 * q] : make_float4(0.f, 0.f, 0.f, 0.f);
    }
    __syncthreads();
    diag_pass_pre(Yt, jb, tid, 1, td);
    offdiag_pass(Mb, Yt, jb, 0, jb, tid, cg, rg);
  }
  __syncthreads();

  // fused marginals: out row i = cgl+1 from K column cgl (local col c)
  const int* mrow = mask + (size_t)b * NN;
  const float* sb = scores + (size_t)b * NN * NN;
  float* ob = out1 + (size_t)b * OSTRIDE;
  for (int c = 0; c < 32; ++c) {
    int cgl = c0 + c;
    if (cgl >= MS) break;
    int i = cgl + 1;
    float* orow = ob + (size_t)i * NN;
    if (mrow[i] == 0) {
      orow[tid] = 0.0f;
    } else {
      float kd = Yt[YW(i - 1, c)];
      int k = tid;
      bool mk = (k == 0) || (mrow[k] != 0);
      float v = 0.0f;
      if (mk) {
        float s2 = (k >= 1) ? Yt[YW(k - 1, c)] : 0.0f;
        v = expf(sb[(size_t)i * NN + k]) * (kd - s2);
      }
      orow[k] = v;
    }
  }
  if (cb == 0) ob[tid] = 0.0f;         // root row i = 0
}

__global__ void k_final(const double* __restrict__ ld2,
                        const double* __restrict__ goldb,
                        const int* __restrict__ cntb, float* __restrict__ out) {
  int tid = threadIdx.x;
  double lz = 0.0, g = 0.0;
  double cnt = 0.0;
  for (int s = tid; s < 8 * BATCH; s += 256) lz += ld2[s];
  if (tid < BATCH) { g = goldb[tid]; cnt = (double)cntb[tid]; }
  __shared__ double r0[256], r1[256], r2[256];
  r0[tid] = lz; r1[tid] = g; r2[tid] = cnt;
  __syncthreads();
  for (int s = 128; s > 0; s >>= 1) {
    if (tid < s) { r0[tid] += r0[tid + s]; r1[tid] += r1[tid + s]; r2[tid] += r2[tid + s]; }
    __syncthreads();
  }
  if (tid == 0) out[0] = (float)((r0[0] - r1[0]) / r2[0]);
}

extern "C" void kernel_launch(void* const* d_in, const int* in_sizes, int n_in,
                              void* d_out, int out_size, void* d_ws, size_t ws_size,
                              hipStream_t stream) {
  const float* scores = (const float*)d_in[0];
  const void* mask_raw = d_in[1];
  const void* tgt_raw = d_in[2];
  float* out = (float*)d_out;
  float* out1 = out + 1;

  float* Mbuf = (float*)d_ws;
  size_t moff = (MSTRIDE * BATCH * sizeof(float) + 255) & ~(size_t)255;
  double* ld2 = (double*)((char*)d_ws + moff);
  double* goldb = ld2 + 8 * BATCH;
  int* cntb = (int*)(goldb + BATCH);
  int* cmask = cntb + BATCH;
  int* ctgt = cmask + BATCH * NN;

  k_convert_gold<<<BATCH, 256, 0, stream>>>(mask_raw, tgt_raw, scores,
                                            cmask, ctgt, goldb, cntb);
  k_build_M<<<dim3(MS, BATCH), 256, 0, stream>>>(scores, cmask, Mbuf);

  k_panel64<<<BATCH, 512, 0, stream>>>(Mbuf, 0, ld2);
  for (int kb = 0; kb + PB < MS; kb += PB) {
    int rem2 = MS - kb - PB;
    int nt64 = (rem2 + 63) / 64;
    k_trsm<<<dim3(nt64, 2, BATCH), 256, 0, stream>>>(Mbuf, kb);
    int nt128 = (rem2 + 127) / 128;
    k_update<<<dim3(nt128, nt128, BATCH), 256, 0, stream>>>(Mbuf, kb);
    k_panel64<<<BATCH, 512, 0, stream>>>(Mbuf, kb + PB, ld2);
  }

  k_solve<<<dim3(1024), 512, 0, stream>>>(Mbuf, scores, cmask, out1);
  k_final<<<1, 256, 0, stream>>>(ld2, goldb, cntb, out);
}

// Round 22
// 1153.654 us; speedup vs baseline: 1.3035x; 1.3035x over previous
//
#include <hip/hip_runtime.h>
#include <math.h>

#define BATCH 64
#define NN 512
#define MS 511                       // minor size (root row/col removed)
#define LDM 512                      // row stride
#define MSTRIDE ((size_t)MS*LDM)
#define OSTRIDE ((size_t)NN*NN)
#define PB 64
// Yt[512][32] words; 4-word rotation by row-octet -> b128-aligned, even bank spread
#define YW(r,c) (((r)<<5) + ((((c) + ((((r)>>3)&7)<<2))) & 31))

// ---- input conversion + gold score + mask count (fused, one pass) ----
__global__ void k_convert_gold(const void* __restrict__ mask_raw,
                               const void* __restrict__ tgt_raw,
                               const float* __restrict__ scores,
                               int* __restrict__ cmask, int* __restrict__ ctgt,
                               double* __restrict__ goldb, int* __restrict__ cntb) {
  int b = blockIdx.x;
  const unsigned char* mb = (const unsigned char*)mask_raw;
  const int* mw = (const int*)mask_raw;
  const int* tw = (const int*)tgt_raw;
  bool m_bytes = (mb[1] | mb[2] | mb[3]) != 0;
  bool m_64 = false;
  if (!m_bytes) {
    int acc = 0;
    for (int j = 1; j < 32; j += 2) acc |= mw[j];
    m_64 = (acc == 0);
  }
  int tacc = 0;
  for (int j = 1; j < 32; j += 2) tacc |= tw[j];
  bool t_64 = (tacc == 0);
  int tid = threadIdx.x;
  double g = 0.0;
  int c = 0;
  for (int i = tid; i < NN; i += 256) {
    size_t idx = (size_t)b * NN + i;
    int mv;
    if (m_bytes) mv = mb[idx] != 0;
    else if (m_64) mv = mw[2 * idx] != 0;
    else mv = mw[idx] != 0;
    int tv = t_64 ? tw[2 * idx] : tw[idx];
    cmask[idx] = mv;
    ctgt[idx] = tv;
    if (mv) {
      g += (double)scores[((size_t)b * NN + i) * NN + tv];
      c++;
    }
  }
  __shared__ double gs[256];
  __shared__ int cs[256];
  gs[tid] = g;
  cs[tid] = c;
  __syncthreads();
  for (int s = 128; s > 0; s >>= 1) {
    if (tid < s) { gs[tid] += gs[tid + s]; cs[tid] += cs[tid + s]; }
    __syncthreads();
  }
  if (tid == 0) { goldb[b] = gs[0]; cntb[b] = cs[0]; }
}

// ---- build Laplacian minor M[b]; pad column (index MS) zeroed ----
__global__ void k_build_M(const float* __restrict__ scores,
                          const int* __restrict__ mask,
                          float* __restrict__ M) {
  int b = blockIdx.y;
  int ip = blockIdx.x;
  int i = ip + 1;
  const int* mrow = mask + (size_t)b * NN;
  float* Mrow = M + (size_t)b * MSTRIDE + (size_t)ip * LDM;
  int tid = threadIdx.x;
  if (!mrow[i]) {
    for (int jp = tid; jp < MS; jp += 256)
      Mrow[jp] = (jp == ip) ? 1.0f : 0.0f;
    if (tid == 0) Mrow[MS] = 0.0f;
    return;
  }
  const float* srow = scores + ((size_t)b * NN + i) * NN;
  double part = 0.0;
  for (int j = tid; j < NN; j += 256) {
    bool mj = (j == 0) || (mrow[j] != 0);
    float e = mj ? expf(srow[j]) : 0.0f;
    part += (double)e;
    if (j >= 1) Mrow[j - 1] = -e;
  }
  __shared__ double red[256];
  red[tid] = part;
  __syncthreads();
  for (int s = 128; s > 0; s >>= 1) {
    if (tid < s) red[tid] += red[tid + s];
    __syncthreads();
  }
  if (tid == (i & 255)) Mrow[ip] += (float)red[0];
  if (tid == 0) Mrow[MS] = 0.0f;
}

// ---- factor 64x64 diag block (512 thr, 8 subs); write PACKED inv ----
__global__ __launch_bounds__(512) void k_panel64(float* __restrict__ M, int kb,
                                                 double* __restrict__ ld2) {
  int b = blockIdx.x;
  float* Mb = M + (size_t)b * MSTRIDE;
  int tid = threadIdx.x;
  __shared__ float A[64 * 65];
  __shared__ float XU[64 * 66];
  __shared__ float XL[64 * 66];
  __shared__ double lg[64];

  for (int idx = tid; idx < 64 * 64; idx += 512) {
    int r = idx >> 6, c = idx & 63;
    int gr = kb + r, gc = kb + c;
    A[r * 65 + c] = (gr < MS && gc < MS) ? Mb[(size_t)gr * LDM + gc]
                                         : ((r == c) ? 1.0f : 0.0f);
  }
  __syncthreads();

  int rr = tid >> 3, sub = tid & 7;   // 8 subs per row, same wave
  for (int j = 0; j < 63; ++j) {
    if (rr > j) {
      float piv = A[j * 65 + j];
      float l = A[rr * 65 + j] / piv;  // all subs read before sub0 writes
      if (sub == 0) A[rr * 65 + j] = l;
      for (int c = j + 1 + sub; c < 64; c += 8)
        A[rr * 65 + c] -= l * A[j * 65 + c];
    }
    __syncthreads();
  }
  if (tid < 64) lg[tid] = log(fabs((double)A[tid * 65 + tid]));
  __syncthreads();
  if (tid == 0) {
    double a = 0.0;
    for (int j = 0; j < 64; ++j) a += lg[j];
    ld2[(kb >> 6) * BATCH + b] = a;
  }

  // invU column rr
  {
    int c = rr;
    if (sub == 0) XU[c * 66 + c] = 1.0f / A[c * 65 + c];
    for (int r2 = c - 1; r2 >= 0; --r2) {
      float s = 0.0f;
      for (int k = r2 + 1 + sub; k <= c; k += 8)
        s += A[r2 * 65 + k] * XU[c * 66 + k];
      s += __shfl_xor(s, 1, 8);
      s += __shfl_xor(s, 2, 8);
      s += __shfl_xor(s, 4, 8);
      if (sub == 0) XU[c * 66 + r2] = -s / A[r2 * 65 + r2];
    }
  }
  // invL column rr (unit lower)
  {
    int c = rr;
    if (sub == 0) XL[c * 66 + c] = 1.0f;
    for (int r2 = c + 1; r2 < 64; ++r2) {
      float s = 0.0f;
      for (int k = c + sub; k < r2; k += 8)
        s += A[r2 * 65 + k] * XL[c * 66 + k];
      s += __shfl_xor(s, 1, 8);
      s += __shfl_xor(s, 2, 8);
      s += __shfl_xor(s, 4, 8);
      if (sub == 0) XL[c * 66 + r2] = -s;
    }
  }
  __syncthreads();
  // packed write into diag block of M
  for (int idx = tid; idx < 4096; idx += 512) {
    int r = idx >> 6, c = idx & 63;
    int gr = kb + r, gc = kb + c;
    if (gr < MS && gc < MS)
      Mb[(size_t)gr * LDM + gc] = (r > c) ? XL[c * 66 + r] : XU[c * 66 + r];
  }
}

// ---- TRSM-as-GEMM using packed inv: side0: U12 = invL*A12 ; side1: L21 = A21*invU ----
__global__ __launch_bounds__(256) void k_trsm(float* __restrict__ M, int kb) {
  int b = blockIdx.z;
  int t = blockIdx.x;
  int side = blockIdx.y;
  float* Mb = M + (size_t)b * MSTRIDE;
  __shared__ float Fs[64 * 65];
  __shared__ float As[64 * 65];
  int tid = threadIdx.x;
  int off = kb + 64 + t * 64;
  for (int idx = tid; idx < 4096; idx += 256) {
    int r = idx >> 6, c = idx & 63;
    int gr = kb + r, gc = kb + c;
    float v;
    if (gr < MS && gc < MS) {
      float d = Mb[(size_t)gr * LDM + gc];
      if (side == 0) v = (r > c) ? d : (r == c ? 1.0f : 0.0f);   // invL
      else           v = (r <= c) ? d : 0.0f;                    // invU
    } else {
      v = (r == c) ? 1.0f : 0.0f;                                // pad identity
    }
    Fs[r * 65 + c] = v;
  }
  for (int idx = tid; idx < 4096; idx += 256) {
    int r = idx >> 6, c = idx & 63;
    int gr, gc;
    if (side == 0) { gr = kb + r; gc = off + c; }
    else           { gr = off + r; gc = kb + c; }
    As[r * 65 + c] = (gr < MS && gc < MS) ? Mb[(size_t)gr * LDM + gc] : 0.0f;
  }
  __syncthreads();
  int tx = tid & 15, ty = tid >> 4;
  float acc[4][4];
#pragma unroll
  for (int i = 0; i < 4; ++i)
#pragma unroll
    for (int j = 0; j < 4; ++j) acc[i][j] = 0.0f;
  if (side == 0) {
#pragma unroll 4
    for (int k = 0; k < 64; ++k) {
      float av[4], bv[4];
#pragma unroll
      for (int i = 0; i < 4; ++i) av[i] = Fs[(ty * 4 + i) * 65 + k];
#pragma unroll
      for (int j = 0; j < 4; ++j) bv[j] = As[k * 65 + tx * 4 + j];
#pragma unroll
      for (int i = 0; i < 4; ++i)
#pragma unroll
        for (int j = 0; j < 4; ++j) acc[i][j] = fmaf(av[i], bv[j], acc[i][j]);
    }
  } else {
#pragma unroll 4
    for (int k = 0; k < 64; ++k) {
      float av[4], bv[4];
#pragma unroll
      for (int i = 0; i < 4; ++i) av[i] = As[(ty * 4 + i) * 65 + k];
#pragma unroll
      for (int j = 0; j < 4; ++j) bv[j] = Fs[k * 65 + tx * 4 + j];
#pragma unroll
      for (int i = 0; i < 4; ++i)
#pragma unroll
        for (int j = 0; j < 4; ++j) acc[i][j] = fmaf(av[i], bv[j], acc[i][j]);
    }
  }
  if (side == 0) {                     // rows kb..kb+63 (<MS); col-511 store = 0 ok
    int gc = off + tx * 4;
    if (gc < MS) {
#pragma unroll
      for (int i = 0; i < 4; ++i) {
        int gr = kb + ty * 4 + i;
        *(float4*)&Mb[(size_t)gr * LDM + gc] =
            make_float4(acc[i][0], acc[i][1], acc[i][2], acc[i][3]);
      }
    }
  } else {                             // cols kb..kb+63 (<MS); guard rows
#pragma unroll
    for (int i = 0; i < 4; ++i) {
      int gr = off + ty * 4 + i;
      if (gr < MS)
        *(float4*)&Mb[(size_t)gr * LDM + kb + tx * 4] =
            make_float4(acc[i][0], acc[i][1], acc[i][2], acc[i][3]);
    }
  }
}

// ---- trailing rank-64 update: C -= L21 * U12, 128x128 tiles, float4 C I/O ----
__global__ __launch_bounds__(256) void k_update(float* __restrict__ M, int kb) {
  int b = blockIdx.z;
  float* Mb = M + (size_t)b * MSTRIDE;
  int row0 = kb + PB + blockIdx.x * 128;
  int col0 = kb + PB + blockIdx.y * 128;
  __shared__ __align__(16) float As[128 * 68];
  __shared__ __align__(16) float Bs[64 * 132];
  int tid = threadIdx.x;
  for (int idx = tid; idx < 2048; idx += 256) {
    int r = idx >> 4, q = (idx & 15) * 4;
    int gr = row0 + r;
    float4 v = make_float4(0.f, 0.f, 0.f, 0.f);
    if (gr < MS) v = *(const float4*)&Mb[(size_t)gr * LDM + kb + q];
    *(float4*)&As[r * 68 + q] = v;
  }
  for (int idx = tid; idx < 2048; idx += 256) {
    int r = idx >> 5, q = (idx & 31) * 4;
    int gc = col0 + q;
    float4 v = make_float4(0.f, 0.f, 0.f, 0.f);
    if (gc < MS)                       // col 511 is maintained 0 in M
      v = *(const float4*)&Mb[(size_t)(kb + r) * LDM + gc];
    *(float4*)&Bs[r * 132 + q] = v;
  }
  __syncthreads();
  int tx = tid & 15, ty = tid >> 4;
  int gc0 = col0 + tx * 4, gc1 = gc0 + 64;
  bool c0v = gc0 < MS, c1v = gc1 < MS;
  float4 acc[8][2];
#pragma unroll
  for (int i = 0; i < 8; ++i) {
    int gr = row0 + ty + 16 * i;
    bool rv = gr < MS;
    acc[i][0] = (rv && c0v) ? *(const float4*)&Mb[(size_t)gr * LDM + gc0]
                            : make_float4(0.f, 0.f, 0.f, 0.f);
    acc[i][1] = (rv && c1v) ? *(const float4*)&Mb[(size_t)gr * LDM + gc1]
                            : make_float4(0.f, 0.f, 0.f, 0.f);
  }
#pragma unroll 2
  for (int k = 0; k < 64; ++k) {
    float4 b0 = *(const float4*)&Bs[k * 132 + tx * 4];
    float4 b1 = *(const float4*)&Bs[k * 132 + tx * 4 + 64];
    float av[8];
#pragma unroll
    for (int i = 0; i < 8; ++i) av[i] = As[(ty + 16 * i) * 68 + k];
#pragma unroll
    for (int i = 0; i < 8; ++i) {
      float a = av[i];
      acc[i][0].x = fmaf(-a, b0.x, acc[i][0].x);
      acc[i][0].y = fmaf(-a, b0.y, acc[i][0].y);
      acc[i][0].z = fmaf(-a, b0.z, acc[i][0].z);
      acc[i][0].w = fmaf(-a, b0.w, acc[i][0].w);
      acc[i][1].x = fmaf(-a, b1.x, acc[i][1].x);
      acc[i][1].y = fmaf(-a, b1.y, acc[i][1].y);
      acc[i][1].z = fmaf(-a, b1.z, acc[i][1].z);
      acc[i][1].w = fmaf(-a, b1.w, acc[i][1].w);
    }
  }
#pragma unroll
  for (int i = 0; i < 8; ++i) {
    int gr = row0 + ty + 16 * i;
    if (gr < MS) {
      if (c0v) *(float4*)&Mb[(size_t)gr * LDM + gc0] = acc[i][0];
      if (c1v) *(float4*)&Mb[(size_t)gr * LDM + gc1] = acc[i][1];
    }
  }
}

// ======== k_solve (R17/R20 known-good): 512 threads, 8 rows x 4 cols/thread ========
__device__ __forceinline__ void diag_pass(const float* __restrict__ Mb,
                                          float* __restrict__ Yt,
                                          int jb, int tid, int UPPER) {
  int drg = tid >> 3, dcg = tid & 7;   // 64 rows x 8 col-groups (4 cols each)
  int dr = jb + drg;
  bool vr = dr < MS;
  const float* Pr = Mb + (size_t)dr * LDM + jb;
  float4 da = make_float4(0.f, 0.f, 0.f, 0.f);
#pragma unroll 4
  for (int q = 0; q < 16; ++q) {
    float4 t = vr ? *(const float4*)&Pr[4 * q] : make_float4(0.f, 0.f, 0.f, 0.f);
#pragma unroll
    for (int m = 0; m < 4; ++m) {
      int cc = 4 * q + m;
      float tm = (m == 0) ? t.x : ((m == 1) ? t.y : ((m == 2) ? t.z : t.w));
      float a;
      if (UPPER) a = (drg <= cc) ? tm : 0.0f;
      else       a = (drg > cc) ? tm : ((drg == cc) ? 1.0f : 0.0f);
      float4 bv = *(const float4*)&Yt[YW(jb + cc, 4 * dcg)];
      da.x = fmaf(a, bv.x, da.x); da.y = fmaf(a, bv.y, da.y);
      da.z = fmaf(a, bv.z, da.z); da.w = fmaf(a, bv.w, da.w);
    }
  }
  __syncthreads();                 // all reads of Y[jb] done before overwrite
  *(float4*)&Yt[YW(jb + drg, 4 * dcg)] = da;
  __syncthreads();
}

// off-diag: rows [rowBase, rowBase+nr) -= A(rows, jb..jb+63) * Y[jb..jb+63]
__device__ __forceinline__ void offdiag_pass(const float* __restrict__ Mb,
                                             float* __restrict__ Yt,
                                             int jb, int rowBase, int nr,
                                             int tid, int cg, int rg) {
  if (nr <= 0) return;
  int row0 = rowBase + 8 * rg;
  int nv = nr - 8 * rg;
  if (nv <= 0) return;
  nv = nv > 8 ? 8 : nv;
  float4 a0[8];
#pragma unroll
  for (int i = 0; i < 8; ++i)
    a0[i] = (i < nv) ? *(const float4*)&Yt[YW(row0 + i, 4 * cg)]
                     : make_float4(0.f, 0.f, 0.f, 0.f);
  const float* Ar = Mb + (size_t)row0 * LDM + jb;
#pragma unroll 2
  for (int kh = 0; kh < 16; ++kh) {
    float4 pA[8];
#pragma unroll
    for (int i = 0; i < 8; ++i)
      pA[i] = (i < nv) ? *(const float4*)&Ar[(size_t)i * LDM + 4 * kh]
                       : make_float4(0.f, 0.f, 0.f, 0.f);
    __builtin_amdgcn_s_setprio(1);
#pragma unroll
    for (int k = 0; k < 4; ++k) {
      float4 bv = *(const float4*)&Yt[YW(jb + 4 * kh + k, 4 * cg)];
#define AK(i) ((k == 0) ? pA[i].x : ((k == 1) ? pA[i].y : ((k == 2) ? pA[i].z : pA[i].w)))
#define RF(i) { \
      float av_ = AK(i); \
      a0[i].x = fmaf(-av_, bv.x, a0[i].x); a0[i].y = fmaf(-av_, bv.y, a0[i].y); \
      a0[i].z = fmaf(-av_, bv.z, a0[i].z); a0[i].w = fmaf(-av_, bv.w, a0[i].w); }
      RF(0) RF(1) RF(2) RF(3) RF(4) RF(5) RF(6) RF(7)
#undef RF
#undef AK
    }
    __builtin_amdgcn_s_setprio(0);
  }
#pragma unroll
  for (int i = 0; i < 8; ++i) {
    if (i < nv)
      *(float4*)&Yt[YW(row0 + i, 4 * cg)] = a0[i];
  }
}

__global__ __launch_bounds__(512, 4) void k_solve(const float* __restrict__ M,
                                                  const float* __restrict__ scores,
                                                  const int* __restrict__ mask,
                                                  float* __restrict__ out1) {
  int id = blockIdx.x;
  int xcd = id & 7, k7 = id >> 3;
  int b = xcd + ((k7 >> 4) << 3);      // 8 batches per XCD, sequential
  int cb = k7 & 15;                    // column block 0..15
  const float* Mb = M + (size_t)b * MSTRIDE;
  int tid = threadIdx.x;
  int c0 = cb * 32, fb = c0 & ~63;
  __shared__ __align__(16) float Yt[512 * 32];   // 65536 B -> 2 WG/CU (16 waves)
  int cg = tid & 7, rg = tid >> 3;

  for (int idx = tid; idx < 4096; idx += 512)
    ((float4*)Yt)[idx] = make_float4(0.f, 0.f, 0.f, 0.f);
  __syncthreads();
  {  // init rows fb..fb+63 = packed invL columns (c0-fb)..+31
    int coff = c0 - fb;
    int r2 = tid >> 3, q4 = (tid & 7) << 2;      // exactly 512 work items
    int gr = fb + r2;
    int c_ = coff + q4;
    float e0, e1, e2, e3;
    if (gr < MS) {
      float4 d = *(const float4*)&Mb[(size_t)gr * LDM + fb + c_];
      e0 = (r2 > c_) ? d.x : ((r2 == c_) ? 1.f : 0.f);
      e1 = (r2 > c_ + 1) ? d.y : ((r2 == c_ + 1) ? 1.f : 0.f);
      e2 = (r2 > c_ + 2) ? d.z : ((r2 == c_ + 2) ? 1.f : 0.f);
      e3 = (r2 > c_ + 3) ? d.w : ((r2 == c_ + 3) ? 1.f : 0.f);
    } else {
      e0 = (r2 == c_) ? 1.f : 0.f;
      e1 = (r2 == c_ + 1) ? 1.f : 0.f;
      e2 = (r2 == c_ + 2) ? 1.f : 0.f;
      e3 = (r2 == c_ + 3) ? 1.f : 0.f;
    }
    *(float4*)&Yt[YW(gr, q4)] = make_float4(e0, e1, e2, e3);
  }
  __syncthreads();

  // forward: L Y = I
  for (int jb = fb; jb < MS; jb += 64) {
    if (jb > fb) {
      __syncthreads();
      diag_pass(Mb, Yt, jb, tid, 0);
    }
    offdiag_pass(Mb, Yt, jb, jb + 64, MS - (jb + 64), tid, cg, rg);
  }
  // backward: U X = Y
  for (int jb = 448; jb >= 0; jb -= 64) {
    __syncthreads();
    diag_pass(Mb, Yt, jb, tid, 1);
    offdiag_pass(Mb, Yt, jb, 0, jb, tid, cg, rg);
  }
  __syncthreads();

  // fused marginals: out row i = cgl+1 from K column cgl (local col c)
  const int* mrow = mask + (size_t)b * NN;
  const float* sb = scores + (size_t)b * NN * NN;
  float* ob = out1 + (size_t)b * OSTRIDE;
  for (int c = 0; c < 32; ++c) {
    int cgl = c0 + c;
    if (cgl >= MS) break;
    int i = cgl + 1;
    float* orow = ob + (size_t)i * NN;
    if (mrow[i] == 0) {
      orow[tid] = 0.0f;
    } else {
      float kd = Yt[YW(i - 1, c)];
      int k = tid;
      bool mk = (k == 0) || (mrow[k] != 0);
      float v = 0.0f;
      if (mk) {
        float s2 = (k >= 1) ? Yt[YW(k - 1, c)] : 0.0f;
        v = expf(sb[(size_t)i * NN + k]) * (kd - s2);
      }
      orow[k] = v;
    }
  }
  if (cb == 0) ob[tid] = 0.0f;         // root row i = 0
}

__global__ void k_final(const double* __restrict__ ld2,
                        const double* __restrict__ goldb,
                        const int* __restrict__ cntb, float* __restrict__ out) {
  int tid = threadIdx.x;
  double lz = 0.0, g = 0.0;
  double cnt = 0.0;
  for (int s = tid; s < 8 * BATCH; s += 256) lz += ld2[s];
  if (tid < BATCH) { g = goldb[tid]; cnt = (double)cntb[tid]; }
  __shared__ double r0[256], r1[256], r2[256];
  r0[tid] = lz; r1[tid] = g; r2[tid] = cnt;
  __syncthreads();
  for (int s = 128; s > 0; s >>= 1) {
    if (tid < s) { r0[tid] += r0[tid + s]; r1[tid] += r1[tid + s]; r2[tid] += r2[tid + s]; }
    __syncthreads();
  }
  if (tid == 0) out[0] = (float)((r0[0] - r1[0]) / r2[0]);
}

extern "C" void kernel_launch(void* const* d_in, const int* in_sizes, int n_in,
                              void* d_out, int out_size, void* d_ws, size_t ws_size,
                              hipStream_t stream) {
  const float* scores = (const float*)d_in[0];
  const void* mask_raw = d_in[1];
  const void* tgt_raw = d_in[2];
  float* out = (float*)d_out;
  float* out1 = out + 1;

  float* Mbuf = (float*)d_ws;
  size_t moff = (MSTRIDE * BATCH * sizeof(float) + 255) & ~(size_t)255;
  double* ld2 = (double*)((char*)d_ws + moff);
  double* goldb = ld2 + 8 * BATCH;
  int* cntb = (int*)(goldb + BATCH);
  int* cmask = cntb + BATCH;
  int* ctgt = cmask + BATCH * NN;

  k_convert_gold<<<BATCH, 256, 0, stream>>>(mask_raw, tgt_raw, scores,
                                            cmask, ctgt, goldb, cntb);
  k_build_M<<<dim3(MS, BATCH), 256, 0, stream>>>(scores, cmask, Mbuf);

  k_panel64<<<BATCH, 512, 0, stream>>>(Mbuf, 0, ld2);
  for (int kb = 0; kb + PB < MS; kb += PB) {
    int rem2 = MS - kb - PB;
    int nt64 = (rem2 + 63) / 64;
    k_trsm<<<dim3(nt64, 2, BATCH), 256, 0, stream>>>(Mbuf, kb);
    int nt128 = (rem2 + 127) / 128;
    k_update<<<dim3(nt128, nt128, BATCH), 256, 0, stream>>>(Mbuf, kb);
    k_panel64<<<BATCH, 512, 0, stream>>>(Mbuf, kb + PB, ld2);
  }

  k_solve<<<dim3(1024), 512, 0, stream>>>(Mbuf, scores, cmask, out1);
  k_final<<<1, 256, 0, stream>>>(ld2, goldb, cntb, out);
}